// Round 9
// baseline (119.195 us; speedup 1.0000x reference)
//
#include <hip/hip_runtime.h>
#include <hip/hip_bf16.h>

// Problem constants
#define BB 8
#define HH 640
#define WW 640
#define HWN (HH * WW)          // 409600 pixels per batch
#define NUM_INST 16
#define NBLK 256               // blocks per batch -> 2048 total = exactly 8 blocks/CU
#define NBLK_TOT (NBLK * BB)
#define THREADS 256
#define NV 36                  // 16 s12 | 16 cnt | pos, all, or, posCnt
#define VEC_PER_BLK 400        // 400 float4 per block; 256*400 = 102400 = HWN/4 exactly

// ws layout: ws[v * NBLK_TOT + g], g = b*NBLK + blockIdx.x. 36*2048*4 = 294912 B.
// Plain stores, no zero-init needed.

__device__ __forceinline__ void process_pixel(
    float p1, float p2, float c, float t, int k,
    float* s12, unsigned* cnt_s,
    float& lgPos, float& lgAll, float& lgOr, float& accCnt)
{
    float andp = p1 * p2;
    bool tpos = (t != 0.0f);
    bool cpos = (c != 0.0f);
    // BCE(and_preds, overlap): overlap exactly 0/1 -> one log, select the argument.
    // Clip at -100 never engages: inputs in [1e-4, 1-1e-4] -> log arg >= ~2e-8.
    float argA = tpos ? andp : (1.0f - andp);
    float lg = __logf(argA);
    lgAll += lg;
    lgPos = fmaf(c, lg, lgPos);        // c is exactly 0.0/1.0
    accCnt += c;
    // BCE(max(p1,p2), conf): conf exactly 0/1
    float mx = fmaxf(p1, p2);
    float argO = cpos ? mx : (1.0f - mx);
    lgOr += __logf(argO);
    // instance term: |d1-d2| = |s1-s2|/cnt, accumulate e1-e2 only
    float ao = t * andp;               // t is exactly 0.0/1.0
    float d1 = fmaxf(p1, ao) - 1.0f;
    float d2 = fmaxf(p2, ao) - 1.0f;
    float e12 = (d1 - d2) * (d1 + d2);
    #pragma unroll
    for (int j = 0; j < NUM_INST; ++j) {
        bool m = (k == j);
        s12[j] += m ? e12 : 0.0f;                       // v_cmp (shared) + cndmask + add
        cnt_s[j] += (unsigned)__popcll(__ballot(m));    // s_bcnt1 + s_add, exec-masked
    }
}

__global__ __launch_bounds__(THREADS, 8) void overlap_main_kernel(
    const float* __restrict__ preds, const float* __restrict__ conf,
    const int* __restrict__ inst, const float* __restrict__ overlap,
    float* __restrict__ ws)
{
    const int b   = blockIdx.y;
    const int tid = threadIdx.x;

    const float4* p1v = (const float4*)(preds + (size_t)b * 2 * HWN);
    const float4* p2v = (const float4*)(preds + (size_t)b * 2 * HWN + HWN);
    const float4* cv  = (const float4*)(conf    + (size_t)b * HWN);
    const float4* tv  = (const float4*)(overlap + (size_t)b * HWN);
    const int4*   kv  = (const int4*)(inst      + (size_t)b * HWN);

    float s12[NUM_INST];
    unsigned cnt_s[NUM_INST];
    #pragma unroll
    for (int j = 0; j < NUM_INST; ++j) { s12[j] = 0.0f; cnt_s[j] = 0u; }
    float lgPos = 0.0f, lgAll = 0.0f, lgOr = 0.0f, accCnt = 0.0f;

    // Block slab: 400 consecutive float4s. Iter A: all 256 threads; iter B: tid<144.
    // Identical shape in every block -> perfect CU balance at 8 blocks/CU.
    const int base = blockIdx.x * VEC_PER_BLK + tid;
    {
        const int i = base;
        float4 A = p1v[i];
        float4 B = p2v[i];
        float4 C = cv[i];
        float4 T = tv[i];
        int4   K = kv[i];
        process_pixel(A.x, B.x, C.x, T.x, K.x, s12, cnt_s, lgPos, lgAll, lgOr, accCnt);
        process_pixel(A.y, B.y, C.y, T.y, K.y, s12, cnt_s, lgPos, lgAll, lgOr, accCnt);
        process_pixel(A.z, B.z, C.z, T.z, K.z, s12, cnt_s, lgPos, lgAll, lgOr, accCnt);
        process_pixel(A.w, B.w, C.w, T.w, K.w, s12, cnt_s, lgPos, lgAll, lgOr, accCnt);
    }
    if (tid < 144) {
        const int i = base + THREADS;
        float4 A = p1v[i];
        float4 B = p2v[i];
        float4 C = cv[i];
        float4 T = tv[i];
        int4   K = kv[i];
        process_pixel(A.x, B.x, C.x, T.x, K.x, s12, cnt_s, lgPos, lgAll, lgOr, accCnt);
        process_pixel(A.y, B.y, C.y, T.y, K.y, s12, cnt_s, lgPos, lgAll, lgOr, accCnt);
        process_pixel(A.z, B.z, C.z, T.z, K.z, s12, cnt_s, lgPos, lgAll, lgOr, accCnt);
        process_pixel(A.w, B.w, C.w, T.w, K.w, s12, cnt_s, lgPos, lgAll, lgOr, accCnt);
    }

    // Butterfly-reduce the 20 per-lane floats (cnt bins are wave-uniform SGPRs)
    float fv[20];
    #pragma unroll
    for (int j = 0; j < NUM_INST; ++j) fv[j] = s12[j];
    fv[16] = lgPos; fv[17] = lgAll; fv[18] = lgOr; fv[19] = accCnt;
    #pragma unroll
    for (int s = 32; s > 0; s >>= 1) {
        #pragma unroll
        for (int v = 0; v < 20; ++v) fv[v] += __shfl_xor(fv[v], s, 64);
    }

    __shared__ float wsum[4][NV];
    const int wave = tid >> 6;
    const int lane = tid & 63;
    if (lane == 0) {
        #pragma unroll
        for (int j = 0; j < NUM_INST; ++j) {
            wsum[wave][j]      = fv[j];
            wsum[wave][16 + j] = (float)cnt_s[j];
        }
        wsum[wave][32] = -fv[16];   // posSum = -sum(c*log)
        wsum[wave][33] = -fv[17];   // allSum = -sum(log)
        wsum[wave][34] = -fv[18];   // orSum  = -sum(log)
        wsum[wave][35] = fv[19];    // posCnt
    }
    __syncthreads();
    if (tid < NV) {
        float s = wsum[0][tid] + wsum[1][tid] + wsum[2][tid] + wsum[3][tid];
        int g = blockIdx.y * NBLK + blockIdx.x;
        ws[tid * NBLK_TOT + g] = s;   // plain store, no atomics
    }
}

__global__ __launch_bounds__(576) void overlap_finalize_kernel(
    const float* __restrict__ ws, float* __restrict__ out)
{
    __shared__ float seg[BB][NV];
    __shared__ float perkey[BB][NUM_INST];
    __shared__ float pres[BB][NUM_INST];
    __shared__ float binst[BB];
    const int t = threadIdx.x;   // 576 = 2 * (8*36)

    {
        int row  = t >> 1;          // 0..287
        int half = t & 1;
        int b = row / NV, v = row - (row / NV) * NV;
        const float4* p = (const float4*)(ws + v * NBLK_TOT + b * NBLK) + half * 32;
        float4 s4 = {0.0f, 0.0f, 0.0f, 0.0f};
        #pragma unroll 8
        for (int i = 0; i < 32; ++i) {     // 2 x 32 float4 = 256 floats per (b,v)
            float4 q = p[i];
            s4.x += q.x; s4.y += q.y; s4.z += q.z; s4.w += q.w;
        }
        float s = (s4.x + s4.y) + (s4.z + s4.w);
        s += __shfl_xor(s, 1, 64);         // combine the two halves
        if (half == 0 && row < BB * NV) seg[b][v] = s;
    }
    __syncthreads();

    if (t < BB * NUM_INST) {
        int b = t >> 4, k = t & 15;
        float c = seg[b][16 + k];
        bool present = c > 0.0f;
        float sc = present ? c : 1.0f;
        perkey[b][k] = present ? (1.0f - fabsf(seg[b][k]) / sc) : 0.0f;
        pres[b][k]   = present ? 1.0f : 0.0f;
    }
    __syncthreads();

    if (t < BB) {
        float s = 0.0f, nk = 0.0f;
        for (int k = 0; k < NUM_INST; ++k) { s += perkey[t][k]; nk += pres[t][k]; }
        binst[t] = s / nk;
    }
    __syncthreads();

    if (t == 0) {
        float instLoss = 0.0f, posS = 0.0f, allS = 0.0f, orS = 0.0f, posC = 0.0f;
        for (int b = 0; b < BB; ++b) {
            instLoss += binst[b];
            posS += seg[b][32];
            allS += seg[b][33];
            orS  += seg[b][34];
            posC += seg[b][35];
        }
        instLoss *= (1.0f / (float)BB);
        const float N = (float)BB * (float)HWN;
        float negS = allS - posS;
        float andLoss = posS / posC + negS / (N - posC);
        float orLoss  = orS / N;
        out[0] = 0.5f * andLoss + 0.25f * orLoss + 0.25f * instLoss;
    }
}

extern "C" void kernel_launch(void* const* d_in, const int* in_sizes, int n_in,
                              void* d_out, int out_size, void* d_ws, size_t ws_size,
                              hipStream_t stream) {
    const float* preds   = (const float*)d_in[0];
    const float* conf    = (const float*)d_in[1];
    const int*   inst    = (const int*)d_in[2];
    const float* overlap = (const float*)d_in[3];
    // d_in[4] (inds) is unused by the reference computation.
    float* ws  = (float*)d_ws;
    float* out = (float*)d_out;

    dim3 grid(NBLK, BB);
    overlap_main_kernel<<<grid, THREADS, 0, stream>>>(preds, conf, inst, overlap, ws);
    overlap_finalize_kernel<<<1, 576, 0, stream>>>(ws, out);
}

// Round 10
// 110.717 us; speedup vs baseline: 1.0766x; 1.0766x over previous
//
#include <hip/hip_runtime.h>
#include <hip/hip_bf16.h>

// Problem constants
#define BB 8
#define HH 640
#define WW 640
#define HWN (HH * WW)            // 409600 pixels per batch
#define NUM_INST 16
#define NBLK_TOT 1024            // flat grid; 4 blocks/CU exactly
#define THREADS 256
#define NV 36                    // 16 s12 | 16 cnt | pos, all, or, posCnt
#define SLAB 800                 // vec4s per block; 800*1024 = 819200 = B*HWN/4 exactly
                                 // 102400/800 = 128 -> no block straddles a batch

// ws layout: ws[v * NBLK_TOT + g], g = flat block id. 36*1024*4 = 147456 B.
// Plain stores, no zero-init needed.

__device__ __forceinline__ void process_pixel(
    float p1, float p2, float c, float t, int k,
    float* s12, unsigned* cnt_s,
    float& lgPos, float& lgAll, float& lgOr, float& accCnt)
{
    float andp = p1 * p2;
    bool tpos = (t != 0.0f);
    bool cpos = (c != 0.0f);
    // BCE(and_preds, overlap): overlap exactly 0/1 -> one log, select the argument.
    // Clip at -100 never engages: inputs in [1e-4, 1-1e-4] -> log arg >= ~2e-8.
    float argA = tpos ? andp : (1.0f - andp);
    float lg = __logf(argA);
    lgAll += lg;
    lgPos = fmaf(c, lg, lgPos);        // c is exactly 0.0/1.0
    accCnt += c;
    // BCE(max(p1,p2), conf): conf exactly 0/1
    float mx = fmaxf(p1, p2);
    float argO = cpos ? mx : (1.0f - mx);
    lgOr += __logf(argO);
    // instance term: |d1-d2| = |s1-s2|/cnt, accumulate e1-e2 only
    float ao = t * andp;               // t is exactly 0.0/1.0
    float d1 = fmaxf(p1, ao) - 1.0f;
    float d2 = fmaxf(p2, ao) - 1.0f;
    float e12 = (d1 - d2) * (d1 + d2);
    #pragma unroll
    for (int j = 0; j < NUM_INST; ++j) {
        bool m = (k == j);
        s12[j] += m ? e12 : 0.0f;                       // v_cmp (shared) + cndmask + add
        cnt_s[j] += (unsigned)__popcll(__ballot(m));    // s_bcnt1 + s_add, exec-masked
    }
}

__global__ __launch_bounds__(THREADS) void overlap_main_kernel(
    const float* __restrict__ preds, const float* __restrict__ conf,
    const int* __restrict__ inst, const float* __restrict__ overlap,
    float* __restrict__ ws)
{
    const int g   = blockIdx.x;          // 0..1023
    const int b   = g >> 7;              // batch
    const int tid = threadIdx.x;
    const int off = (g & 127) * SLAB;    // vec4 offset within batch

    const float4* p1v = (const float4*)(preds + (size_t)b * 2 * HWN) + off;
    const float4* p2v = (const float4*)(preds + (size_t)b * 2 * HWN + HWN) + off;
    const float4* cv  = (const float4*)(conf    + (size_t)b * HWN) + off;
    const float4* tv  = (const float4*)(overlap + (size_t)b * HWN) + off;
    const int4*   kv  = (const int4*)(inst      + (size_t)b * HWN) + off;

    float s12[NUM_INST];
    unsigned cnt_s[NUM_INST];
    #pragma unroll
    for (int j = 0; j < NUM_INST; ++j) { s12[j] = 0.0f; cnt_s[j] = 0u; }
    float lgPos = 0.0f, lgAll = 0.0f, lgOr = 0.0f, accCnt = 0.0f;

    // Hoist ALL loads for the 3 uniform iterations: 15 outstanding vec4 loads
    // per thread (one vmcnt drain amortized over 3 iterations of compute).
    float4 A[3], B[3], C[3], T[3];
    int4   K[3];
    #pragma unroll
    for (int it = 0; it < 3; ++it) {
        const int i = tid + it * THREADS;
        A[it] = p1v[i];
        B[it] = p2v[i];
        C[it] = cv[i];
        T[it] = tv[i];
        K[it] = kv[i];
    }
    #pragma unroll
    for (int it = 0; it < 3; ++it) {
        process_pixel(A[it].x, B[it].x, C[it].x, T[it].x, K[it].x, s12, cnt_s, lgPos, lgAll, lgOr, accCnt);
        process_pixel(A[it].y, B[it].y, C[it].y, T[it].y, K[it].y, s12, cnt_s, lgPos, lgAll, lgOr, accCnt);
        process_pixel(A[it].z, B[it].z, C[it].z, T[it].z, K[it].z, s12, cnt_s, lgPos, lgAll, lgOr, accCnt);
        process_pixel(A[it].w, B[it].w, C[it].w, T[it].w, K[it].w, s12, cnt_s, lgPos, lgAll, lgOr, accCnt);
    }
    // Remainder: 32 threads cover vec4s [768, 800). Exec-masked ballot stays exact.
    if (tid < SLAB - 3 * THREADS) {
        const int i = tid + 3 * THREADS;
        float4 a = p1v[i];
        float4 bq = p2v[i];
        float4 cq = cv[i];
        float4 tq = tv[i];
        int4   kq = kv[i];
        process_pixel(a.x, bq.x, cq.x, tq.x, kq.x, s12, cnt_s, lgPos, lgAll, lgOr, accCnt);
        process_pixel(a.y, bq.y, cq.y, tq.y, kq.y, s12, cnt_s, lgPos, lgAll, lgOr, accCnt);
        process_pixel(a.z, bq.z, cq.z, tq.z, kq.z, s12, cnt_s, lgPos, lgAll, lgOr, accCnt);
        process_pixel(a.w, bq.w, cq.w, tq.w, kq.w, s12, cnt_s, lgPos, lgAll, lgOr, accCnt);
    }

    // Butterfly-reduce the 20 per-lane floats (cnt bins are wave-uniform SGPRs)
    float fv[20];
    #pragma unroll
    for (int j = 0; j < NUM_INST; ++j) fv[j] = s12[j];
    fv[16] = lgPos; fv[17] = lgAll; fv[18] = lgOr; fv[19] = accCnt;
    #pragma unroll
    for (int s = 32; s > 0; s >>= 1) {
        #pragma unroll
        for (int v = 0; v < 20; ++v) fv[v] += __shfl_xor(fv[v], s, 64);
    }

    __shared__ float wsum[4][NV];
    const int wave = tid >> 6;
    const int lane = tid & 63;
    if (lane == 0) {
        #pragma unroll
        for (int j = 0; j < NUM_INST; ++j) {
            wsum[wave][j]      = fv[j];
            wsum[wave][16 + j] = (float)cnt_s[j];
        }
        wsum[wave][32] = -fv[16];   // posSum = -sum(c*log)
        wsum[wave][33] = -fv[17];   // allSum = -sum(log)
        wsum[wave][34] = -fv[18];   // orSum  = -sum(log)
        wsum[wave][35] = fv[19];    // posCnt
    }
    __syncthreads();
    if (tid < NV) {
        float s = wsum[0][tid] + wsum[1][tid] + wsum[2][tid] + wsum[3][tid];
        ws[tid * NBLK_TOT + g] = s;   // plain store, no atomics
    }
}

__global__ __launch_bounds__(320) void overlap_finalize_kernel(
    const float* __restrict__ ws, float* __restrict__ out)
{
    __shared__ float seg[BB][NV];
    __shared__ float perkey[BB][NUM_INST];
    __shared__ float pres[BB][NUM_INST];
    __shared__ float binst[BB];
    const int t = threadIdx.x;   // 320 >= 8*36 = 288

    if (t < BB * NV) {
        int b = t / NV, v = t - (t / NV) * NV;
        // batch b's blocks are g in [b*128, (b+1)*128)
        const float4* p = (const float4*)(ws + v * NBLK_TOT + b * 128);
        float4 s4 = {0.0f, 0.0f, 0.0f, 0.0f};
        #pragma unroll 8
        for (int i = 0; i < 32; ++i) {   // 128 floats per (b,v)
            float4 q = p[i];
            s4.x += q.x; s4.y += q.y; s4.z += q.z; s4.w += q.w;
        }
        seg[b][v] = (s4.x + s4.y) + (s4.z + s4.w);
    }
    __syncthreads();

    if (t < BB * NUM_INST) {
        int b = t >> 4, k = t & 15;
        float c = seg[b][16 + k];
        bool present = c > 0.0f;
        float sc = present ? c : 1.0f;
        perkey[b][k] = present ? (1.0f - fabsf(seg[b][k]) / sc) : 0.0f;
        pres[b][k]   = present ? 1.0f : 0.0f;
    }
    __syncthreads();

    if (t < BB) {
        float s = 0.0f, nk = 0.0f;
        for (int k = 0; k < NUM_INST; ++k) { s += perkey[t][k]; nk += pres[t][k]; }
        binst[t] = s / nk;
    }
    __syncthreads();

    if (t == 0) {
        float instLoss = 0.0f, posS = 0.0f, allS = 0.0f, orS = 0.0f, posC = 0.0f;
        for (int b = 0; b < BB; ++b) {
            instLoss += binst[b];
            posS += seg[b][32];
            allS += seg[b][33];
            orS  += seg[b][34];
            posC += seg[b][35];
        }
        instLoss *= (1.0f / (float)BB);
        const float N = (float)BB * (float)HWN;
        float negS = allS - posS;
        float andLoss = posS / posC + negS / (N - posC);
        float orLoss  = orS / N;
        out[0] = 0.5f * andLoss + 0.25f * orLoss + 0.25f * instLoss;
    }
}

extern "C" void kernel_launch(void* const* d_in, const int* in_sizes, int n_in,
                              void* d_out, int out_size, void* d_ws, size_t ws_size,
                              hipStream_t stream) {
    const float* preds   = (const float*)d_in[0];
    const float* conf    = (const float*)d_in[1];
    const int*   inst    = (const int*)d_in[2];
    const float* overlap = (const float*)d_in[3];
    // d_in[4] (inds) is unused by the reference computation.
    float* ws  = (float*)d_ws;
    float* out = (float*)d_out;

    overlap_main_kernel<<<NBLK_TOT, THREADS, 0, stream>>>(preds, conf, inst, overlap, ws);
    overlap_finalize_kernel<<<1, 320, 0, stream>>>(ws, out);
}